// Round 6
// baseline (908.293 us; speedup 1.0000x reference)
//
#include <hip/hip_runtime.h>
#include <math.h>

// Problem constants
#define IN_CH  256
#define OUT_CH 256
#define WDIM   512
#define BATCH  16
#define HH     128

typedef _Float16 f16;
typedef f16   f16x8 __attribute__((ext_vector_type(8)));
typedef float f32x4 __attribute__((ext_vector_type(4)));

#define NCOL 130                // 128 data cols + 2 zero halo cols
#define XSLOTS (3 * NCOL * 4)   // uint4 slots per X buffer

// wmod layout: [b][dydx 9][ocg 2][chunk 8][ocl 128][icl 32] f16 (8KB blocks)
__device__ __host__ inline size_t wblock(int b, int dydx, int ocg, int chunk) {
    return ((((size_t)b * 9 + dydx) * 2 + ocg) * 8 + chunk) * 4096;
}
// wT layout: [r 9][ocg 2][chunk 8][ocl 128][icl 32] f32 (batch-independent)
__device__ inline size_t wtoff(int r, int ocg, int chunk, int ocl, int icl) {
    return ((((size_t)r * 2 + ocg) * 8 + chunk) * 128 + ocl) * 32 + icl;
}

// ---------------------------------------------------------------------------
// style[b][i] = (w[b] . mod_weight[i]) * mod_scale + bias[i].  grid (4,16)x64
// ---------------------------------------------------------------------------
__global__ void style_kernel(const float* __restrict__ w,
                             const float* __restrict__ mod_weight,
                             const float* __restrict__ mod_bias,
                             float* __restrict__ style) {
    const int b = blockIdx.y;
    const int i = blockIdx.x * 64 + threadIdx.x;
    const float4* wp = (const float4*)(w + (size_t)b * WDIM);
    const float4* mp = (const float4*)(mod_weight + (size_t)i * WDIM);
    float acc = 0.f;
#pragma unroll 8
    for (int j = 0; j < WDIM / 4; ++j) {
        float4 a = wp[j], c = mp[j];
        acc += a.x * c.x + a.y * c.y + a.z * c.z + a.w * c.w;
    }
    style[b * IN_CH + i] = acc * (1.0f / sqrtf((float)WDIM)) + mod_bias[i];
}

// ---------------------------------------------------------------------------
// Transpose weight -> wT[r][ocg][chunk][ocl][icl] f32, fused q[oc][ic]=sum_r w^2
// grid 256 (oc), 64 threads; thread t handles ic = 4t..4t+3
// ---------------------------------------------------------------------------
__global__ void wt_kernel(const float* __restrict__ weight,
                          float* __restrict__ wT,
                          float* __restrict__ q) {
    const int oc = blockIdx.x, t = threadIdx.x;
    const int ocg = oc >> 7, ocl = oc & 127;
    const float* wp = weight + (size_t)oc * IN_CH * 9 + (size_t)t * 36;
    float v[36];
#pragma unroll
    for (int j = 0; j < 36; ++j) v[j] = wp[j];
    float sq0 = 0.f, sq1 = 0.f, sq2 = 0.f, sq3 = 0.f;
#pragma unroll
    for (int u = 0; u < 4; ++u) {
        const int ic = 4 * t + u;
        const int chunk = ic >> 5, icl = ic & 31;
        float s = 0.f;
#pragma unroll
        for (int r = 0; r < 9; ++r) {
            float xv = v[u * 9 + r];
            s += xv * xv;
            wT[wtoff(r, ocg, chunk, ocl, icl)] = xv;
        }
        if (u == 0) sq0 = s; else if (u == 1) sq1 = s;
        else if (u == 2) sq2 = s; else sq3 = s;
    }
    float4 qv = {sq0, sq1, sq2, sq3};
    *(float4*)(q + (size_t)oc * IN_CH + 4 * t) = qv;
}

// ---------------------------------------------------------------------------
// dfac[b][o] = rsqrt((1/2304) * sum_i style^2 * q + 1e-8). grid (256,16) x 64
// ---------------------------------------------------------------------------
__global__ void demod_kernel(const float* __restrict__ q,
                             const float* __restrict__ style,
                             float* __restrict__ dfac) {
    const int o = blockIdx.x, b = blockIdx.y, t = threadIdx.x;
    float4 qv = *(const float4*)(q + (size_t)o * IN_CH + 4 * t);
    float4 sv = *(const float4*)(style + (size_t)b * IN_CH + 4 * t);
    float s = qv.x * sv.x * sv.x + qv.y * sv.y * sv.y
            + qv.z * sv.z * sv.z + qv.w * sv.w * sv.w;
#pragma unroll
    for (int off = 32; off > 0; off >>= 1) s += __shfl_down(s, off, 64);
    if (t == 0) dfac[b * OUT_CH + o] = rsqrtf(s * (1.0f / 2304.0f) + 1e-8f);
}

// ---------------------------------------------------------------------------
// wmod from wT, fully coalesced both sides. grid (9, 2, 16) x 256
// ---------------------------------------------------------------------------
__global__ void wmod2_kernel(const float* __restrict__ wT,
                             const float* __restrict__ style,
                             const float* __restrict__ dfac,
                             f16* __restrict__ wmod) {
    const int r = blockIdx.x, ocg = blockIdx.y, b = blockIdx.z;
    const int t = threadIdx.x;
    __shared__ float ss[IN_CH];
    __shared__ float dd[128];
    if (t < 128) dd[t] = dfac[b * OUT_CH + ocg * 128 + t];
    ss[t] = style[b * IN_CH + t] * (1.0f / 48.0f);
    __syncthreads();
    const int ocl = t >> 1, icb = (t & 1) * 16;
    const float dv = dd[ocl];
#pragma unroll 1
    for (int chunk = 0; chunk < 8; ++chunk) {
        const float* src = wT + wtoff(r, ocg, chunk, ocl, icb);
        float4 a0 = *(const float4*)(src);
        float4 a1 = *(const float4*)(src + 4);
        float4 a2 = *(const float4*)(src + 8);
        float4 a3 = *(const float4*)(src + 12);
        float vals[16] = {a0.x,a0.y,a0.z,a0.w, a1.x,a1.y,a1.z,a1.w,
                          a2.x,a2.y,a2.z,a2.w, a3.x,a3.y,a3.z,a3.w};
        union { f16 h[16]; uint4 u[2]; } ob;
#pragma unroll
        for (int j = 0; j < 16; ++j)
            ob.h[j] = (f16)(vals[j] * ss[chunk * 32 + icb + j] * dv);
        uint4* dst = (uint4*)(wmod + wblock(b, r, ocg, chunk) + (size_t)ocl * 32 + icb);
        dst[0] = ob.u[0];
        dst[1] = ob.u[1];
    }
}

// ---------------------------------------------------------------------------
// OLD wmod path (tier2 fallback, proven round-3): strided reads of weight.
// ---------------------------------------------------------------------------
__global__ void wsq_kernel(const float* __restrict__ weight,
                           float* __restrict__ q) {
    const int o = blockIdx.x, i = threadIdx.x;
    const float* wp = weight + ((size_t)o * IN_CH + i) * 9;
    float s = 0.f;
#pragma unroll
    for (int r = 0; r < 9; ++r) { float v = wp[r]; s += v * v; }
    q[o * IN_CH + i] = s;
}

__global__ void wmod_kernel(const float* __restrict__ weight,
                            const float* __restrict__ style,
                            const float* __restrict__ dfac,
                            f16* __restrict__ wmod) {
    const int r = blockIdx.x, ocg = blockIdx.y, b = blockIdx.z;
    const int t = threadIdx.x;
    const int ocl = t >> 1, half = t & 1;
    const int oc = ocg * 128 + ocl;
    const float sd = dfac[b * OUT_CH + oc] * (1.0f / 48.0f);
    const float* wp = weight + (size_t)oc * IN_CH * 9 + r;
    const float* sp = style + (size_t)b * IN_CH;
    for (int chunk = 0; chunk < 8; ++chunk) {
        const int icb = chunk * 32 + half * 16;
        union { f16 h[16]; uint4 u[2]; } buf;
#pragma unroll
        for (int j = 0; j < 16; ++j) {
            const int ic = icb + j;
            buf.h[j] = (f16)(wp[(size_t)ic * 9] * sp[ic] * sd);
        }
        uint4* dst = (uint4*)(wmod + wblock(b, r, ocg, chunk) + (size_t)ocl * 32 + half * 16);
        dst[0] = buf.u[0];
        dst[1] = buf.u[1];
    }
}

// ---------------------------------------------------------------------------
// Implicit-GEMM conv via mfma_f32_16x16x32_f16.
// Block: 256 thr = 4 waves, tile M=256 oc x N=128 cols (one y row), grid 2048.
// Wave w: 64 oc (ocg=w>>1, 64-block=(w&1)*64) x 128 cols; acc[4][8].
// A direct from global (L2-resident) with 2-dydx-ahead register ring af[3][4].
// X f16 double-buffered LDS, one barrier per ic-chunk (288 MFMA/barrier).
// ---------------------------------------------------------------------------
__global__ __launch_bounds__(256, 2) void conv_mfma(
        const float* __restrict__ x,
        const f16*  __restrict__ wmod,
        float* __restrict__ out) {
    __shared__ uint4 xs4[2 * XSLOTS];    // 2 x 24960 B

    // bijective XCD swizzle: 2048 blocks, 8 XCDs, 256 per XCD; adjacent y same XCD
    const int bid = blockIdx.x;
    const int lid = (bid & 7) * 256 + (bid >> 3);
    const int y0  = lid & 127;
    const int b   = lid >> 7;

    const int t  = threadIdx.x;
    const int l  = t & 63;
    const int w  = t >> 6;
    const int wocg = w >> 1;            // which ocg half this wave owns
    const int wo64 = (w & 1) * 64;      // 64-oc sub-block within ocg
    const int lm = l & 15, lg = l >> 4;

    f32x4 acc[4][8];
#pragma unroll
    for (int i = 0; i < 4; ++i)
#pragma unroll
        for (int j = 0; j < 8; ++j) acc[i][j] = (f32x4){0.f, 0.f, 0.f, 0.f};

    // zero halo cols (c=0,129) in both buffers
    if (t < 48) {
        int buf = t / 24, rem = t - 24 * buf;
        int blk = rem >> 2;
        int r = blk >> 1;
        int c = (blk & 1) ? 129 : 0;
        uint4 z = {0u, 0u, 0u, 0u};
        xs4[buf * XSLOTS + (r * NCOL + c) * 4 + (rem & 3)] = z;
    }

    const int cq = t & 31;   // col-quad: cols 1+4cq..+3
    const int gq = t >> 5;   // ic-quad:  ics 4gq..+3

    auto stageX = [&](int chunk, int buf) {
        const int ic0 = chunk * 32;
        uint4* xbuf = xs4 + buf * XSLOTS;
#pragma unroll
        for (int r = 0; r < 3; ++r) {
            const int gy = y0 - 1 + r;
            float vv[4][4];
            if (gy >= 0 && gy < HH) {
#pragma unroll
                for (int rr = 0; rr < 4; ++rr) {
                    const float* gp = x + (((size_t)(b * IN_CH + ic0 + 4 * gq + rr)) * HH + gy) * HH + 4 * cq;
                    float4 qv = *(const float4*)gp;
                    vv[rr][0] = qv.x; vv[rr][1] = qv.y; vv[rr][2] = qv.z; vv[rr][3] = qv.w;
                }
            } else {
#pragma unroll
                for (int rr = 0; rr < 4; ++rr)
#pragma unroll
                    for (int cc = 0; cc < 4; ++cc) vv[rr][cc] = 0.f;
            }
#pragma unroll
            for (int cc = 0; cc < 4; ++cc) {
                const int c = 1 + 4 * cq + cc;
                const int lsel = ((gq >> 1) + (c >> 2)) & 3;
                union { f16 h[4]; uint2 u2; } pk;
                pk.h[0] = (f16)vv[0][cc]; pk.h[1] = (f16)vv[1][cc];
                pk.h[2] = (f16)vv[2][cc]; pk.h[3] = (f16)vv[3][cc];
                char* p = (char*)xbuf + (((size_t)r * NCOL + c) << 6) + (lsel << 4) + ((gq & 1) << 3);
                *(uint2*)p = pk.u2;
            }
        }
    };

    auto aload = [&](int chunk, int dydx, f16x8 (&dst)[4]) {
        const f16* p = wmod + wblock(b, dydx, wocg, chunk);
#pragma unroll
        for (int mt = 0; mt < 4; ++mt) {
            const int ocl = wo64 + mt * 16 + lm;
            dst[mt] = *(const f16x8*)(p + (size_t)ocl * 32 + lg * 8);
        }
    };

    f16x8 af0[4], af1[4], af2[4];
    aload(0, 0, af0);
    aload(0, 1, af1);
    stageX(0, 0);
    __syncthreads();

    auto mma_blk = [&](const uint4* xbuf, int dy, int dx, f16x8 (&a)[4]) {
#pragma unroll
        for (int nt = 0; nt < 8; ++nt) {
            const int c = nt * 16 + lm + dx;
            const int lsel = (lg + (c >> 2)) & 3;
            const char* bp = (const char*)xbuf + (((size_t)dy * NCOL + c) << 6) + (lsel << 4);
            f16x8 bf = *(const f16x8*)bp;
#pragma unroll
            for (int mt = 0; mt < 4; ++mt) {
                acc[mt][nt] = __builtin_amdgcn_mfma_f32_16x16x32_f16(a[mt], bf, acc[mt][nt], 0, 0, 0);
            }
        }
    };

    int cur = 0;
    for (int chunk = 0; chunk < 8; ++chunk) {
        if (chunk < 7) stageX(chunk + 1, cur ^ 1);
        const uint4* xbuf = xs4 + cur * XSLOTS;
#pragma unroll
        for (int dydx = 0; dydx < 9; ++dydx) {
            // prefetch A for iteration k+2 into the ring slot it will be used from
            int nd = dydx + 2, nb = chunk;
            if (nd >= 9) { nd -= 9; nb += 1; }
            const int psel = (dydx + 2) % 3;   // compile-time after unroll
            if (nb < 8) {
                if (psel == 0) aload(nb, nd, af0);
                else if (psel == 1) aload(nb, nd, af1);
                else aload(nb, nd, af2);
            }
            const int dy = dydx / 3;
            const int dx = dydx - 3 * dy;
            const int sel = dydx % 3;
            if (sel == 0) mma_blk(xbuf, dy, dx, af0);
            else if (sel == 1) mma_blk(xbuf, dy, dx, af1);
            else mma_blk(xbuf, dy, dx, af2);
        }
        __syncthreads();
        cur ^= 1;
    }

    // epilogue: oc = wocg*128 + wo64 + mt*16 + lg*4 + reg; col = nt*16 + lm
#pragma unroll
    for (int mt = 0; mt < 4; ++mt) {
#pragma unroll
        for (int nt = 0; nt < 8; ++nt) {
            const int col = nt * 16 + lm;
#pragma unroll
            for (int reg = 0; reg < 4; ++reg) {
                const int oc = wocg * 128 + wo64 + mt * 16 + lg * 4 + reg;
                out[(((size_t)(b * OUT_CH + oc)) * HH + y0) * HH + col] = acc[mt][nt][reg];
            }
        }
    }
}

// ---------------------------------------------------------------------------
// fp32 direct-conv ultimate fallback (round-1, proven)
// ---------------------------------------------------------------------------
#define TILE_H 32
#define TILE_W 64
#define OCB    8
#define ICH    4
#define XS_COLS 66
#define XS_STRIDE 68
#define XS_ROWS 34

__global__ void demod_fb_kernel(const float* __restrict__ weight,
                                const float* __restrict__ style,
                                float* __restrict__ dfac) {
    const int b = blockIdx.x;
    const int o = threadIdx.x;
    __shared__ float s2[IN_CH];
    for (int j = threadIdx.x; j < IN_CH; j += 256) {
        float s = style[b * IN_CH + j];
        s2[j] = s * s;
    }
    __syncthreads();
    float acc2 = 0.f;
    const float* wp = weight + (size_t)o * IN_CH * 9;
    for (int i = 0; i < IN_CH; ++i) {
        float sq = 0.f;
#pragma unroll
        for (int r = 0; r < 9; ++r) { float v = wp[i * 9 + r]; sq += v * v; }
        acc2 += sq * s2[i];
    }
    dfac[b * OUT_CH + o] = rsqrtf(acc2 * (1.0f / 2304.0f) + 1e-8f);
}

__global__ __launch_bounds__(256, 3) void conv_kernel(
        const float* __restrict__ x,
        const float* __restrict__ weight,
        const float* __restrict__ style,
        const float* __restrict__ dfac,
        float* __restrict__ out) {
    __shared__ float xs[ICH][XS_ROWS * XS_STRIDE];
    __shared__ float wsm[ICH][OCB][12];

    const int tile = blockIdx.x;
    const int ocg  = blockIdx.y;
    const int b    = blockIdx.z;
    const int y0 = (tile >> 1) * TILE_H;
    const int x0 = (tile & 1) * TILE_W;

    const int t  = threadIdx.x;
    const int ty = t >> 3;
    const int tx = t & 7;

    float acc[OCB][8];
#pragma unroll
    for (int o = 0; o < OCB; ++o)
#pragma unroll
        for (int j = 0; j < 8; ++j) acc[o][j] = 0.f;

    const float* xb = x + (size_t)b * IN_CH * HH * HH;
    const float* stb = style + b * IN_CH;
    const float* dfb = dfac + b * OUT_CH;

    for (int ic0 = 0; ic0 < IN_CH; ic0 += ICH) {
        __syncthreads();
        for (int icl = 0; icl < ICH; ++icl) {
            const float* xc = xb + (size_t)(ic0 + icl) * HH * HH;
            for (int s = t; s < XS_ROWS * XS_COLS; s += 256) {
                int row = s / XS_COLS;
                int col = s - row * XS_COLS;
                int gy = y0 + row - 1;
                int gx = x0 + col - 1;
                float v = 0.f;
                if (gy >= 0 && gy < HH && gx >= 0 && gx < HH) v = xc[gy * HH + gx];
                xs[icl][row * XS_STRIDE + col] = v;
            }
        }
        for (int s = t; s < ICH * OCB * 9; s += 256) {
            int icl = s / (OCB * 9);
            int rem = s - icl * (OCB * 9);
            int o   = rem / 9;
            int r   = rem - o * 9;
            int oc  = ocg * OCB + o;
            int ic  = ic0 + icl;
            float wv = weight[((size_t)oc * IN_CH + ic) * 9 + r];
            wsm[icl][o][r] = wv * ((1.0f / 48.0f) * stb[ic] * dfb[oc]);
        }
        __syncthreads();
#pragma unroll 1
        for (int icl = 0; icl < ICH; ++icl) {
            float xr[3][10];
#pragma unroll
            for (int dy = 0; dy < 3; ++dy) {
                const float* p = &xs[icl][(ty + dy) * XS_STRIDE + 8 * tx];
                float4 a  = *(const float4*)(p);
                float4 bv = *(const float4*)(p + 4);
                float2 c  = *(const float2*)(p + 8);
                xr[dy][0] = a.x;  xr[dy][1] = a.y;  xr[dy][2] = a.z;  xr[dy][3] = a.w;
                xr[dy][4] = bv.x; xr[dy][5] = bv.y; xr[dy][6] = bv.z; xr[dy][7] = bv.w;
                xr[dy][8] = c.x;  xr[dy][9] = c.y;
            }
#pragma unroll
            for (int o = 0; o < OCB; ++o) {
                const float* wp = wsm[icl][o];
                float w0 = wp[0], w1 = wp[1], w2 = wp[2];
                float w3 = wp[3], w4 = wp[4], w5 = wp[5];
                float w6 = wp[6], w7 = wp[7], w8 = wp[8];
#pragma unroll
                for (int j = 0; j < 8; ++j) {
                    acc[o][j] += w0 * xr[0][j]     + w1 * xr[0][j + 1] + w2 * xr[0][j + 2]
                               + w3 * xr[1][j]     + w4 * xr[1][j + 1] + w5 * xr[1][j + 2]
                               + w6 * xr[2][j]     + w7 * xr[2][j + 1] + w8 * xr[2][j + 2];
                }
            }
        }
    }

    const int gy = y0 + ty;
    const int gx = x0 + 8 * tx;
#pragma unroll
    for (int o = 0; o < OCB; ++o) {
        int oc = ocg * OCB + o;
        float* op = out + (((size_t)b * OUT_CH + oc) * HH + gy) * HH + gx;
        float4 v0 = {acc[o][0], acc[o][1], acc[o][2], acc[o][3]};
        float4 v1 = {acc[o][4], acc[o][5], acc[o][6], acc[o][7]};
        *(float4*)(op)     = v0;
        *(float4*)(op + 4) = v1;
    }
}

// ---------------------------------------------------------------------------
extern "C" void kernel_launch(void* const* d_in, const int* in_sizes, int n_in,
                              void* d_out, int out_size, void* d_ws, size_t ws_size,
                              hipStream_t stream) {
    const float* x          = (const float*)d_in[0];
    const float* w          = (const float*)d_in[1];
    const float* weight     = (const float*)d_in[2];
    const float* mod_weight = (const float*)d_in[3];
    const float* mod_bias   = (const float*)d_in[4];
    float* out = (float*)d_out;

    // ws layout: style 16KB | dfac 16KB | q 256KB | [wT 9.4MB] | wmod 18.9MB
    float* style = (float*)d_ws;
    float* dfac  = style + BATCH * IN_CH;
    float* q     = dfac + BATCH * OUT_CH;
    const size_t base = 16384 + 16384 + 262144;
    const size_t wT_bytes   = (size_t)9 * 2 * 8 * 128 * 32 * sizeof(float);   // 9.44 MB
    const size_t wmod_bytes = (size_t)BATCH * 9 * 2 * 8 * 4096 * sizeof(f16); // 18.9 MB

    const size_t need_new = base + wT_bytes + wmod_bytes;
    const size_t need_old = base + wmod_bytes;

    style_kernel<<<dim3(4, BATCH), dim3(64), 0, stream>>>(w, mod_weight, mod_bias, style);

    if (ws_size >= need_new) {
        float* wT   = (float*)((char*)d_ws + base);
        f16*  wmodp = (f16*)((char*)d_ws + base + wT_bytes);
        wt_kernel<<<dim3(256), dim3(64), 0, stream>>>(weight, wT, q);
        demod_kernel<<<dim3(256, BATCH), dim3(64), 0, stream>>>(q, style, dfac);
        wmod2_kernel<<<dim3(9, 2, BATCH), dim3(256), 0, stream>>>(wT, style, dfac, wmodp);
        conv_mfma<<<dim3(2048), dim3(256), 0, stream>>>(x, wmodp, out);
    } else if (ws_size >= need_old) {
        f16* wmodp = (f16*)((char*)d_ws + base);
        wsq_kernel<<<dim3(256), dim3(256), 0, stream>>>(weight, q);
        demod_kernel<<<dim3(256, BATCH), dim3(64), 0, stream>>>(q, style, dfac);
        wmod_kernel<<<dim3(9, 2, BATCH), dim3(256), 0, stream>>>(weight, style, dfac, wmodp);
        conv_mfma<<<dim3(2048), dim3(256), 0, stream>>>(x, wmodp, out);
    } else {
        demod_fb_kernel<<<dim3(BATCH), dim3(256), 0, stream>>>(weight, style, dfac);
        conv_kernel<<<dim3(8, 32, BATCH), dim3(256), 0, stream>>>(x, weight, style, dfac, out);
    }
}